// Round 1
// baseline (1465.855 us; speedup 1.0000x reference)
//
#include <hip/hip_runtime.h>

#define IN_DIM 256
#define OUT_DIM 32
#define KITER 10

// ---------------- preprocessing kernels ----------------

__global__ void hist_kernel(const int* __restrict__ col, int E,
                            unsigned int* __restrict__ cnt) {
    int i = blockIdx.x * blockDim.x + threadIdx.x;
    if (i < E) atomicAdd(&cnt[col[i]], 1u);
}

__global__ void dinv_kernel(const unsigned int* __restrict__ cnt, int N,
                            float* __restrict__ dinv) {
    int i = blockIdx.x * blockDim.x + threadIdx.x;
    if (i < N) dinv[i] = rsqrtf((float)(cnt[i] + 1u));  // +1 self loop, always > 0
}

// single-block exclusive scan of cnt[0..N) -> off[0..N]
__global__ __launch_bounds__(1024) void scan_kernel(const unsigned int* __restrict__ cnt,
                                                    int N, unsigned int* __restrict__ off) {
    __shared__ unsigned int part[1024];
    int t = threadIdx.x;
    int chunk = (N + 1023) / 1024;
    int base = t * chunk;
    unsigned int s = 0;
    for (int i = 0; i < chunk; ++i) {
        int idx = base + i;
        if (idx < N) s += cnt[idx];
    }
    part[t] = s;
    __syncthreads();
    if (t == 0) {
        unsigned int run = 0;
        for (int i = 0; i < 1024; ++i) {
            unsigned int v = part[i];
            part[i] = run;
            run += v;
        }
    }
    __syncthreads();
    unsigned int run = part[t];
    for (int i = 0; i < chunk; ++i) {
        int idx = base + i;
        if (idx < N) {
            off[idx] = run;
            run += cnt[idx];
        }
    }
    if (t == 1023) off[N] = part[1023] + s;  // total edge count
}

__global__ void scatter_kernel(const int* __restrict__ row, const int* __restrict__ col,
                               int E, const unsigned int* __restrict__ off,
                               unsigned int* __restrict__ cur,
                               const float* __restrict__ dinv,
                               int* __restrict__ srcS, float* __restrict__ wS) {
    int e = blockIdx.x * blockDim.x + threadIdx.x;
    if (e >= E) return;
    int r = row[e];
    int c = col[e];
    unsigned int p = off[c] + atomicAdd(&cur[c], 1u);
    srcS[p] = r;
    wS[p] = dinv[r] * dinv[c];
}

// ---------------- h = x @ W^T + b ----------------
// one thread per output row; W (32x256 f32 = 32KB) staged in LDS, broadcast reads

__global__ __launch_bounds__(256) void gemm_kernel(const float* __restrict__ x,
                                                   const float* __restrict__ W,
                                                   const float* __restrict__ b, int N,
                                                   float* __restrict__ h) {
    __shared__ float4 Wl[OUT_DIM * IN_DIM / 4];  // 2048 float4 = 32 KB
    int tid = threadIdx.x;
    for (int i = tid; i < OUT_DIM * IN_DIM / 4; i += 256)
        Wl[i] = ((const float4*)W)[i];
    __syncthreads();
    int r = blockIdx.x * 256 + tid;
    if (r >= N) return;
    float acc[OUT_DIM];
#pragma unroll
    for (int ch = 0; ch < OUT_DIM; ++ch) acc[ch] = 0.0f;
    const float4* xr = (const float4*)(x + (size_t)r * IN_DIM);
    for (int k4 = 0; k4 < IN_DIM / 4; ++k4) {
        float4 xv = xr[k4];
#pragma unroll
        for (int ch = 0; ch < OUT_DIM; ++ch) {
            float4 wv = Wl[ch * (IN_DIM / 4) + k4];
            acc[ch] += xv.x * wv.x + xv.y * wv.y + xv.z * wv.z + xv.w * wv.w;
        }
    }
    float4* hr = (float4*)(h + (size_t)r * OUT_DIM);
#pragma unroll
    for (int c4 = 0; c4 < OUT_DIM / 4; ++c4) {
        float4 bb = ((const float4*)b)[c4];
        float4 o;
        o.x = acc[c4 * 4 + 0] + bb.x;
        o.y = acc[c4 * 4 + 1] + bb.y;
        o.z = acc[c4 * 4 + 2] + bb.z;
        o.w = acc[c4 * 4 + 3] + bb.w;
        hr[c4] = o;
    }
}

// ---------------- one APPNP propagation step ----------------
// 32 lanes per node (ch = lane&31); coalesced 128B gathers of z[src]

__global__ __launch_bounds__(256) void spmv_kernel(
    const int* __restrict__ srcS, const float* __restrict__ wS,
    const unsigned int* __restrict__ off, const float* __restrict__ dinv,
    const float* __restrict__ zin, const float* __restrict__ h,
    const float* __restrict__ prelu_a, int N, int last, float* __restrict__ zout) {
    int tid = threadIdx.x;
    int ch = tid & 31;
    int node = blockIdx.x * 8 + (tid >> 5);
    if (node >= N) return;
    unsigned int e = off[node];
    unsigned int end = off[node + 1];
    float di = dinv[node];
    float acc = di * di * zin[(size_t)node * OUT_DIM + ch];  // self loop
    if (e < end) {
        // software-pipelined: next edge's (src,w) loads overlap current gather
        int s = srcS[e];
        float w = wS[e];
        for (;;) {
            unsigned int e2 = e + 1;
            int s2 = 0;
            float w2 = 0.0f;
            bool more = (e2 < end);
            if (more) {
                s2 = srcS[e2];
                w2 = wS[e2];
            }
            acc += w * zin[(size_t)s * OUT_DIM + ch];
            if (!more) break;
            e = e2;
            s = s2;
            w = w2;
        }
    }
    float out = 0.8f * acc + 0.2f * h[(size_t)node * OUT_DIM + ch];
    if (last) {
        float a = prelu_a[ch];
        out = (out >= 0.0f) ? out : a * out;
    }
    zout[(size_t)node * OUT_DIM + ch] = out;
}

// ---------------- launcher ----------------

extern "C" void kernel_launch(void* const* d_in, const int* in_sizes, int n_in,
                              void* d_out, int out_size, void* d_ws, size_t ws_size,
                              hipStream_t stream) {
    const float* x = (const float*)d_in[0];
    const int* ei = (const int*)d_in[1];
    const float* W = (const float*)d_in[2];
    const float* b = (const float*)d_in[3];
    const float* pa = (const float*)d_in[4];

    int N = in_sizes[0] / IN_DIM;
    int E = in_sizes[1] / 2;
    const int* row = ei;      // edge_index[0] = source
    const int* col = ei + E;  // edge_index[1] = target

    char* ws = (char*)d_ws;
    size_t o = 0;
    auto alloc = [&](size_t bytes) -> void* {
        void* p = ws + o;
        o += (bytes + 255) & ~(size_t)255;
        return p;
    };
    unsigned int* d_cnt = (unsigned int*)alloc((size_t)N * 4);
    unsigned int* d_off = (unsigned int*)alloc((size_t)(N + 1) * 4);
    unsigned int* d_cur = (unsigned int*)alloc((size_t)N * 4);
    float* d_dinv = (float*)alloc((size_t)N * 4);
    int* d_srcS = (int*)alloc((size_t)E * 4);
    float* d_wS = (float*)alloc((size_t)E * 4);
    float* d_h = (float*)alloc((size_t)N * OUT_DIM * 4);
    float* d_zA = (float*)alloc((size_t)N * OUT_DIM * 4);
    float* d_zB = (float*)alloc((size_t)N * OUT_DIM * 4);

    hipMemsetAsync(d_cnt, 0, (size_t)N * 4, stream);
    hipMemsetAsync(d_cur, 0, (size_t)N * 4, stream);

    hist_kernel<<<(E + 255) / 256, 256, 0, stream>>>(col, E, d_cnt);
    dinv_kernel<<<(N + 255) / 256, 256, 0, stream>>>(d_cnt, N, d_dinv);
    scan_kernel<<<1, 1024, 0, stream>>>(d_cnt, N, d_off);
    scatter_kernel<<<(E + 255) / 256, 256, 0, stream>>>(row, col, E, d_off, d_cur,
                                                        d_dinv, d_srcS, d_wS);
    gemm_kernel<<<(N + 255) / 256, 256, 0, stream>>>(x, W, b, N, d_h);

    float* bufs[2] = {d_zA, d_zB};
    const float* zin = d_h;
    for (int it = 0; it < KITER; ++it) {
        int last = (it == KITER - 1);
        float* zo = last ? (float*)d_out : bufs[it & 1];
        spmv_kernel<<<(N + 7) / 8, 256, 0, stream>>>(d_srcS, d_wS, d_off, d_dinv, zin,
                                                     d_h, pa, N, last, zo);
        zin = zo;
    }
}

// Round 3
// 947.499 us; speedup vs baseline: 1.5471x; 1.5471x over previous
//
#include <hip/hip_runtime.h>

#define IN_DIM 256
#define OUT_DIM 32
#define KITER 10
#define SCAN_TILE 2048

// ---------------- preprocessing ----------------

__global__ void hist_kernel(const int* __restrict__ col, int E,
                            unsigned int* __restrict__ cnt) {
    int i = blockIdx.x * blockDim.x + threadIdx.x;
    if (i < E) atomicAdd(&cnt[col[i]], 1u);
}

// per-tile local exclusive scan (+ tile sums + fused dinv)
__global__ __launch_bounds__(256) void scanA_kernel(const unsigned int* __restrict__ cnt,
                                                    int N, unsigned int* __restrict__ local,
                                                    unsigned int* __restrict__ blkSum,
                                                    float* __restrict__ dinv) {
    __shared__ unsigned int sh[256];
    int t = threadIdx.x;
    int base = blockIdx.x * SCAN_TILE + t * 8;
    unsigned int v[8];
    unsigned int sum = 0;
#pragma unroll
    for (int i = 0; i < 8; ++i) {
        int idx = base + i;
        v[i] = (idx < N) ? cnt[idx] : 0u;
        sum += v[i];
    }
    sh[t] = sum;
    __syncthreads();
#pragma unroll
    for (int d = 1; d < 256; d <<= 1) {
        unsigned int x = (t >= d) ? sh[t - d] : 0u;
        __syncthreads();
        sh[t] += x;
        __syncthreads();
    }
    if (t == 255) blkSum[blockIdx.x] = sh[255];
    unsigned int run = (t > 0) ? sh[t - 1] : 0u;
#pragma unroll
    for (int i = 0; i < 8; ++i) {
        int idx = base + i;
        if (idx < N) {
            local[idx] = run;
            run += v[i];
            dinv[idx] = rsqrtf((float)(v[i] + 1u));  // +1 self loop
        }
    }
}

// scan of tile sums (nb <= 1024), writes blkSum[nb] = total
__global__ __launch_bounds__(256) void scanB_kernel(unsigned int* __restrict__ blkSum, int nb) {
    __shared__ unsigned int sh[1025];
    int t = threadIdx.x;
    for (int i = t; i < nb; i += 256) sh[i] = blkSum[i];
    __syncthreads();
    if (t == 0) {
        unsigned int run = 0;
        for (int i = 0; i < nb; ++i) {
            unsigned int x = sh[i];
            sh[i] = run;
            run += x;
        }
        sh[nb] = run;
    }
    __syncthreads();
    for (int i = t; i <= nb; i += 256) blkSum[i] = sh[i];
}

// add tile offsets; write both off[] and the scatter cursor copy cur[]
__global__ void scanC_kernel(const unsigned int* __restrict__ local,
                             const unsigned int* __restrict__ blkSum, int N, int nb,
                             unsigned int* __restrict__ off, unsigned int* __restrict__ cur) {
    int i = blockIdx.x * blockDim.x + threadIdx.x;
    if (i < N) {
        unsigned int v = local[i] + blkSum[i / SCAN_TILE];
        off[i] = v;
        cur[i] = v;
    } else if (i == N) {
        off[N] = blkSum[nb];
    }
}

// bucket edges by target; pack (src bit-cast, weight) into float2
__global__ void scatter_kernel(const int* __restrict__ row, const int* __restrict__ col,
                               int E, unsigned int* __restrict__ cur,
                               const float* __restrict__ dinv, float2* __restrict__ ew) {
    int e = blockIdx.x * blockDim.x + threadIdx.x;
    if (e >= E) return;
    int r = row[e];
    int c = col[e];
    unsigned int p = atomicAdd(&cur[c], 1u);
    float2 v;
    v.x = __int_as_float(r);
    v.y = dinv[r] * dinv[c];
    ew[p] = v;
}

// ---------------- h = x @ W^T + b ----------------
// one thread per row; W reads are wave-uniform -> scalar loads (no LDS)

__global__ __launch_bounds__(256) void gemm_kernel(const float* __restrict__ x,
                                                   const float* __restrict__ W,
                                                   const float* __restrict__ b, int N,
                                                   float* __restrict__ h) {
    int r = blockIdx.x * 256 + threadIdx.x;
    if (r >= N) return;
    const float4* xr = (const float4*)(x + (size_t)r * IN_DIM);
    const float4* Wp = (const float4*)W;
    float acc[OUT_DIM];
#pragma unroll
    for (int ch = 0; ch < OUT_DIM; ++ch) acc[ch] = 0.0f;
#pragma unroll 4
    for (int k4 = 0; k4 < IN_DIM / 4; ++k4) {
        float4 xv = xr[k4];
#pragma unroll
        for (int ch = 0; ch < OUT_DIM; ++ch) {
            float4 wv = Wp[ch * (IN_DIM / 4) + k4];
            acc[ch] = fmaf(xv.x, wv.x,
                      fmaf(xv.y, wv.y, fmaf(xv.z, wv.z, fmaf(xv.w, wv.w, acc[ch]))));
        }
    }
    float4* hr = (float4*)(h + (size_t)r * OUT_DIM);
#pragma unroll
    for (int c4 = 0; c4 < OUT_DIM / 4; ++c4) {
        float4 bb = ((const float4*)b)[c4];
        float4 o;
        o.x = acc[c4 * 4 + 0] + bb.x;
        o.y = acc[c4 * 4 + 1] + bb.y;
        o.z = acc[c4 * 4 + 2] + bb.z;
        o.w = acc[c4 * 4 + 3] + bb.w;
        hr[c4] = o;
    }
}

// ---------------- one APPNP propagation step ----------------
// 32 lanes per node (ch = lane&31); 4-way unroll -> 4 gathers in flight

__global__ __launch_bounds__(256) void spmv_kernel(
    const float2* __restrict__ ew, const unsigned int* __restrict__ off,
    const float* __restrict__ dinv, const float* __restrict__ zin,
    const float* __restrict__ h, const float* __restrict__ prelu_a, int N, int last,
    float* __restrict__ zout) {
    int tid = threadIdx.x;
    int ch = tid & 31;
    int node = blockIdx.x * 8 + (tid >> 5);
    if (node >= N) return;
    size_t nb32 = (size_t)node * OUT_DIM + ch;
    unsigned int e = off[node];
    unsigned int end = off[node + 1];
    float di = dinv[node];
    float hterm = 0.2f * h[nb32];
    float acc0 = di * di * zin[nb32];  // self loop
    float acc1 = 0.f, acc2 = 0.f, acc3 = 0.f;
    for (; e + 4 <= end; e += 4) {
        float2 p0 = ew[e], p1 = ew[e + 1], p2 = ew[e + 2], p3 = ew[e + 3];
        acc0 += p0.y * zin[(size_t)__float_as_int(p0.x) * OUT_DIM + ch];
        acc1 += p1.y * zin[(size_t)__float_as_int(p1.x) * OUT_DIM + ch];
        acc2 += p2.y * zin[(size_t)__float_as_int(p2.x) * OUT_DIM + ch];
        acc3 += p3.y * zin[(size_t)__float_as_int(p3.x) * OUT_DIM + ch];
    }
    for (; e < end; ++e) {
        float2 p = ew[e];
        acc0 += p.y * zin[(size_t)__float_as_int(p.x) * OUT_DIM + ch];
    }
    float out = 0.8f * ((acc0 + acc1) + (acc2 + acc3)) + hterm;
    if (last) {
        float a = prelu_a[ch];
        out = (out >= 0.f) ? out : a * out;
    }
    zout[nb32] = out;
}

// ---------------- launcher ----------------

extern "C" void kernel_launch(void* const* d_in, const int* in_sizes, int n_in,
                              void* d_out, int out_size, void* d_ws, size_t ws_size,
                              hipStream_t stream) {
    const float* x = (const float*)d_in[0];
    const int* ei = (const int*)d_in[1];
    const float* W = (const float*)d_in[2];
    const float* b = (const float*)d_in[3];
    const float* pa = (const float*)d_in[4];

    int N = in_sizes[0] / IN_DIM;
    int E = in_sizes[1] / 2;
    const int* row = ei;      // edge_index[0] = source
    const int* col = ei + E;  // edge_index[1] = target
    int nb = (N + SCAN_TILE - 1) / SCAN_TILE;

    char* ws = (char*)d_ws;
    size_t o = 0;
    auto alloc = [&](size_t bytes) -> void* {
        void* p = ws + o;
        o += (bytes + 255) & ~(size_t)255;
        return p;
    };
    unsigned int* d_cnt = (unsigned int*)alloc((size_t)N * 4);
    unsigned int* d_local = (unsigned int*)alloc((size_t)N * 4);
    unsigned int* d_blkSum = (unsigned int*)alloc(4096);
    unsigned int* d_off = (unsigned int*)alloc((size_t)(N + 1) * 4);
    unsigned int* d_cur = (unsigned int*)alloc((size_t)N * 4);
    float* d_dinv = (float*)alloc((size_t)N * 4);
    float2* d_ew = (float2*)alloc((size_t)E * 8);
    float* d_h = (float*)alloc((size_t)N * OUT_DIM * 4);
    float* d_zA = (float*)alloc((size_t)N * OUT_DIM * 4);
    float* d_zB = (float*)alloc((size_t)N * OUT_DIM * 4);
    (void)ws_size;

    hipMemsetAsync(d_cnt, 0, (size_t)N * 4, stream);

    hist_kernel<<<(E + 255) / 256, 256, 0, stream>>>(col, E, d_cnt);
    scanA_kernel<<<nb, 256, 0, stream>>>(d_cnt, N, d_local, d_blkSum, d_dinv);
    scanB_kernel<<<1, 256, 0, stream>>>(d_blkSum, nb);
    scanC_kernel<<<(N + 256) / 256, 256, 0, stream>>>(d_local, d_blkSum, N, nb, d_off, d_cur);
    scatter_kernel<<<(E + 255) / 256, 256, 0, stream>>>(row, col, E, d_cur, d_dinv, d_ew);
    gemm_kernel<<<(N + 255) / 256, 256, 0, stream>>>(x, W, b, N, d_h);

    float* bufs[2] = {d_zA, d_zB};
    const float* zin = d_h;
    for (int it = 0; it < KITER; ++it) {
        int last = (it == KITER - 1);
        float* zo = last ? (float*)d_out : bufs[it & 1];
        spmv_kernel<<<(N + 7) / 8, 256, 0, stream>>>(d_ew, d_off, d_dinv, zin, d_h, pa, N,
                                                     last, zo);
        zin = zo;
    }
}

// Round 4
// 896.740 us; speedup vs baseline: 1.6346x; 1.0566x over previous
//
#include <hip/hip_runtime.h>
#include <hip/hip_bf16.h>

#define IN_DIM 256
#define OUT_DIM 32
#define KITER 10
#define SCAN_TILE 2048

// ---------------- preprocessing ----------------

__global__ void hist_kernel(const int* __restrict__ col, int E,
                            unsigned int* __restrict__ cnt) {
    int i = blockIdx.x * blockDim.x + threadIdx.x;
    if (i < E) atomicAdd(&cnt[col[i]], 1u);
}

// per-tile local exclusive scan (+ tile sums + fused dinv)
__global__ __launch_bounds__(256) void scanA_kernel(const unsigned int* __restrict__ cnt,
                                                    int N, unsigned int* __restrict__ local,
                                                    unsigned int* __restrict__ blkSum,
                                                    float* __restrict__ dinv) {
    __shared__ unsigned int sh[256];
    int t = threadIdx.x;
    int base = blockIdx.x * SCAN_TILE + t * 8;
    unsigned int v[8];
    unsigned int sum = 0;
#pragma unroll
    for (int i = 0; i < 8; ++i) {
        int idx = base + i;
        v[i] = (idx < N) ? cnt[idx] : 0u;
        sum += v[i];
    }
    sh[t] = sum;
    __syncthreads();
#pragma unroll
    for (int d = 1; d < 256; d <<= 1) {
        unsigned int x = (t >= d) ? sh[t - d] : 0u;
        __syncthreads();
        sh[t] += x;
        __syncthreads();
    }
    if (t == 255) blkSum[blockIdx.x] = sh[255];
    unsigned int run = (t > 0) ? sh[t - 1] : 0u;
#pragma unroll
    for (int i = 0; i < 8; ++i) {
        int idx = base + i;
        if (idx < N) {
            local[idx] = run;
            run += v[i];
            dinv[idx] = rsqrtf((float)(v[i] + 1u));  // +1 self loop
        }
    }
}

// scan of tile sums (nb <= 1024), writes blkSum[nb] = total
__global__ __launch_bounds__(256) void scanB_kernel(unsigned int* __restrict__ blkSum, int nb) {
    __shared__ unsigned int sh[1025];
    int t = threadIdx.x;
    for (int i = t; i < nb; i += 256) sh[i] = blkSum[i];
    __syncthreads();
    if (t == 0) {
        unsigned int run = 0;
        for (int i = 0; i < nb; ++i) {
            unsigned int x = sh[i];
            sh[i] = run;
            run += x;
        }
        sh[nb] = run;
    }
    __syncthreads();
    for (int i = t; i <= nb; i += 256) blkSum[i] = sh[i];
}

// add tile offsets; write both off[] and the scatter cursor copy cur[]
__global__ void scanC_kernel(const unsigned int* __restrict__ local,
                             const unsigned int* __restrict__ blkSum, int N, int nb,
                             unsigned int* __restrict__ off, unsigned int* __restrict__ cur) {
    int i = blockIdx.x * blockDim.x + threadIdx.x;
    if (i < N) {
        unsigned int v = local[i] + blkSum[i / SCAN_TILE];
        off[i] = v;
        cur[i] = v;
    } else if (i == N) {
        off[N] = blkSum[nb];
    }
}

// bucket edges by target; pack (src bit-cast, weight) into float2
__global__ void scatter_kernel(const int* __restrict__ row, const int* __restrict__ col,
                               int E, unsigned int* __restrict__ cur,
                               const float* __restrict__ dinv, float2* __restrict__ ew) {
    int e = blockIdx.x * blockDim.x + threadIdx.x;
    if (e >= E) return;
    int r = row[e];
    int c = col[e];
    unsigned int p = atomicAdd(&cur[c], 1u);
    float2 v;
    v.x = __int_as_float(r);
    v.y = dinv[r] * dinv[c];
    ew[p] = v;
}

// ---------------- h = x @ W^T + b ----------------
// 64-row tile staged in LDS transposed+XOR-swizzled; coalesced global loads.
// wave w computes channels 8w..8w+7 (wave-uniform -> W via scalar loads);
// lane = row within tile.

__global__ __launch_bounds__(256) void gemm_kernel(const float* __restrict__ x,
                                                   const float* __restrict__ W,
                                                   const float* __restrict__ b, int N,
                                                   float* __restrict__ h) {
    __shared__ float4 tileT[64][64];  // [k4][row ^ (k4&7)] : 64 KB
    int t = threadIdx.x;
    int r0 = blockIdx.x * 64;
    const float4* xg = (const float4*)x + (size_t)r0 * (IN_DIM / 4);
    bool full = (r0 + 64 <= N);
#pragma unroll
    for (int i = 0; i < 16; ++i) {
        int f = i * 256 + t;   // 0..4095, = row*64 + k4 (coalesced)
        int row = f >> 6;
        int k4 = f & 63;
        float4 v = make_float4(0.f, 0.f, 0.f, 0.f);
        if (full || (r0 + row) < N) v = xg[f];
        tileT[k4][row ^ (k4 & 7)] = v;
    }
    __syncthreads();
    int lane = t & 63;
    int ch0 = __builtin_amdgcn_readfirstlane(t >> 6) * 8;  // wave-uniform
    const float4* Wp = (const float4*)W;
    float acc[8];
#pragma unroll
    for (int c = 0; c < 8; ++c) acc[c] = 0.f;
#pragma unroll 4
    for (int k4 = 0; k4 < 64; ++k4) {
        float4 xv = tileT[k4][lane ^ (k4 & 7)];
#pragma unroll
        for (int c = 0; c < 8; ++c) {
            float4 wv = Wp[(ch0 + c) * (IN_DIM / 4) + k4];  // scalar (SGPR) loads
            acc[c] = fmaf(xv.x, wv.x,
                     fmaf(xv.y, wv.y, fmaf(xv.z, wv.z, fmaf(xv.w, wv.w, acc[c]))));
        }
    }
    int row = r0 + lane;
    if (row < N) {
        const float* bb = b + ch0;
        float4 o0, o1;
        o0.x = acc[0] + bb[0]; o0.y = acc[1] + bb[1];
        o0.z = acc[2] + bb[2]; o0.w = acc[3] + bb[3];
        o1.x = acc[4] + bb[4]; o1.y = acc[5] + bb[5];
        o1.z = acc[6] + bb[6]; o1.w = acc[7] + bb[7];
        float4* hr = (float4*)(h + (size_t)row * OUT_DIM + ch0);
        hr[0] = o0;
        hr[1] = o1;
    }
}

// ---------------- one APPNP propagation step ----------------
// 32 lanes per node (ch = lane&31); 4 gathers in flight; bf16 z intermediates

template <bool IN_BF, bool OUT_BF>
__global__ __launch_bounds__(256) void spmv_kernel(
    const float2* __restrict__ ew, const unsigned int* __restrict__ off,
    const float* __restrict__ dinv, const void* __restrict__ zin_v,
    const float* __restrict__ h, const float* __restrict__ prelu_a, int N,
    void* __restrict__ zout_v) {
    const float* zf = (const float*)zin_v;
    const __hip_bfloat16* zb = (const __hip_bfloat16*)zin_v;
    int tid = threadIdx.x;
    int ch = tid & 31;
    int node = blockIdx.x * 8 + (tid >> 5);
    if (node >= N) return;
    size_t nidx = (size_t)node * OUT_DIM + ch;
    unsigned int e = off[node];
    unsigned int end = off[node + 1];
    float di = dinv[node];
    float self = IN_BF ? __bfloat162float(zb[nidx]) : zf[nidx];
    float hterm = 0.2f * h[nidx];
    float acc0 = di * di * self;  // self loop
    float acc1 = 0.f, acc2 = 0.f, acc3 = 0.f;
    auto gz = [&](float sbits) -> float {
        size_t i = (size_t)__float_as_int(sbits) * OUT_DIM + ch;
        return IN_BF ? __bfloat162float(zb[i]) : zf[i];
    };
    for (; e + 4 <= end; e += 4) {
        float2 p0 = ew[e], p1 = ew[e + 1], p2 = ew[e + 2], p3 = ew[e + 3];
        acc0 += p0.y * gz(p0.x);
        acc1 += p1.y * gz(p1.x);
        acc2 += p2.y * gz(p2.x);
        acc3 += p3.y * gz(p3.x);
    }
    for (; e < end; ++e) {
        float2 p = ew[e];
        acc0 += p.y * gz(p.x);
    }
    float out = 0.8f * ((acc0 + acc1) + (acc2 + acc3)) + hterm;
    if (OUT_BF) {
        ((__hip_bfloat16*)zout_v)[nidx] = __float2bfloat16(out);
    } else {
        // final iteration: fuse PReLU, write f32 output
        float a = prelu_a[ch];
        out = (out >= 0.f) ? out : a * out;
        ((float*)zout_v)[nidx] = out;
    }
}

// ---------------- launcher ----------------

extern "C" void kernel_launch(void* const* d_in, const int* in_sizes, int n_in,
                              void* d_out, int out_size, void* d_ws, size_t ws_size,
                              hipStream_t stream) {
    const float* x = (const float*)d_in[0];
    const int* ei = (const int*)d_in[1];
    const float* W = (const float*)d_in[2];
    const float* b = (const float*)d_in[3];
    const float* pa = (const float*)d_in[4];

    int N = in_sizes[0] / IN_DIM;
    int E = in_sizes[1] / 2;
    const int* row = ei;      // edge_index[0] = source
    const int* col = ei + E;  // edge_index[1] = target
    int nb = (N + SCAN_TILE - 1) / SCAN_TILE;

    char* ws = (char*)d_ws;
    size_t o = 0;
    auto alloc = [&](size_t bytes) -> void* {
        void* p = ws + o;
        o += (bytes + 255) & ~(size_t)255;
        return p;
    };
    unsigned int* d_cnt = (unsigned int*)alloc((size_t)N * 4);
    unsigned int* d_local = (unsigned int*)alloc((size_t)N * 4);
    unsigned int* d_blkSum = (unsigned int*)alloc(4096);
    unsigned int* d_off = (unsigned int*)alloc((size_t)(N + 1) * 4);
    unsigned int* d_cur = (unsigned int*)alloc((size_t)N * 4);
    float* d_dinv = (float*)alloc((size_t)N * 4);
    float2* d_ew = (float2*)alloc((size_t)E * 8);
    float* d_h = (float*)alloc((size_t)N * OUT_DIM * 4);
    __hip_bfloat16* d_zA = (__hip_bfloat16*)alloc((size_t)N * OUT_DIM * 2);
    __hip_bfloat16* d_zB = (__hip_bfloat16*)alloc((size_t)N * OUT_DIM * 2);
    (void)ws_size;

    hipMemsetAsync(d_cnt, 0, (size_t)N * 4, stream);

    hist_kernel<<<(E + 255) / 256, 256, 0, stream>>>(col, E, d_cnt);
    scanA_kernel<<<nb, 256, 0, stream>>>(d_cnt, N, d_local, d_blkSum, d_dinv);
    scanB_kernel<<<1, 256, 0, stream>>>(d_blkSum, nb);
    scanC_kernel<<<(N + 256) / 256, 256, 0, stream>>>(d_local, d_blkSum, N, nb, d_off, d_cur);
    scatter_kernel<<<(E + 255) / 256, 256, 0, stream>>>(row, col, E, d_cur, d_dinv, d_ew);
    gemm_kernel<<<(N + 63) / 64, 256, 0, stream>>>(x, W, b, N, d_h);

    int grid = (N + 7) / 8;
    // iter 0: f32 h -> bf16 zA
    spmv_kernel<false, true><<<grid, 256, 0, stream>>>(d_ew, d_off, d_dinv, d_h, d_h, pa, N,
                                                       d_zA);
    // iters 1..8: bf16 -> bf16 (ping-pong)
    __hip_bfloat16* bufs[2] = {d_zA, d_zB};
    for (int it = 1; it < KITER - 1; ++it) {
        spmv_kernel<true, true><<<grid, 256, 0, stream>>>(
            d_ew, d_off, d_dinv, bufs[(it + 1) & 1], d_h, pa, N, bufs[it & 1]);
    }
    // iter 9: bf16 -> f32 out + PReLU
    spmv_kernel<true, false><<<grid, 256, 0, stream>>>(d_ew, d_off, d_dinv, bufs[1], d_h, pa,
                                                       N, d_out);
}

// Round 5
// 835.878 us; speedup vs baseline: 1.7537x; 1.0728x over previous
//
#include <hip/hip_runtime.h>
#include <hip/hip_bf16.h>

#define IN_DIM 256
#define OUT_DIM 32
#define KITER 10
#define SCAN_TILE 2048

typedef __attribute__((ext_vector_type(8))) short short8v;   // 8 x bf16
typedef __attribute__((ext_vector_type(4))) float float4v;   // mfma C/D

// ---------------- preprocessing ----------------

__global__ void hist_kernel(const int* __restrict__ col, int E,
                            unsigned int* __restrict__ cnt) {
    int i = blockIdx.x * blockDim.x + threadIdx.x;
    if (i < E) atomicAdd(&cnt[col[i]], 1u);
}

// per-tile local exclusive scan (+ tile sums + fused dinv)
__global__ __launch_bounds__(256) void scanA_kernel(const unsigned int* __restrict__ cnt,
                                                    int N, unsigned int* __restrict__ local,
                                                    unsigned int* __restrict__ blkSum,
                                                    float* __restrict__ dinv) {
    __shared__ unsigned int sh[256];
    int t = threadIdx.x;
    int base = blockIdx.x * SCAN_TILE + t * 8;
    unsigned int v[8];
    unsigned int sum = 0;
#pragma unroll
    for (int i = 0; i < 8; ++i) {
        int idx = base + i;
        v[i] = (idx < N) ? cnt[idx] : 0u;
        sum += v[i];
    }
    sh[t] = sum;
    __syncthreads();
#pragma unroll
    for (int d = 1; d < 256; d <<= 1) {
        unsigned int x = (t >= d) ? sh[t - d] : 0u;
        __syncthreads();
        sh[t] += x;
        __syncthreads();
    }
    if (t == 255) blkSum[blockIdx.x] = sh[255];
    unsigned int run = (t > 0) ? sh[t - 1] : 0u;
#pragma unroll
    for (int i = 0; i < 8; ++i) {
        int idx = base + i;
        if (idx < N) {
            local[idx] = run;
            run += v[i];
            dinv[idx] = rsqrtf((float)(v[i] + 1u));  // +1 self loop
        }
    }
}

// scan of tile sums (nb <= 1024), writes blkSum[nb] = total
__global__ __launch_bounds__(256) void scanB_kernel(unsigned int* __restrict__ blkSum, int nb) {
    __shared__ unsigned int sh[1025];
    int t = threadIdx.x;
    for (int i = t; i < nb; i += 256) sh[i] = blkSum[i];
    __syncthreads();
    if (t == 0) {
        unsigned int run = 0;
        for (int i = 0; i < nb; ++i) {
            unsigned int x = sh[i];
            sh[i] = run;
            run += x;
        }
        sh[nb] = run;
    }
    __syncthreads();
    for (int i = t; i <= nb; i += 256) blkSum[i] = sh[i];
}

// add tile offsets; write both off[] and the scatter cursor copy cur[]
__global__ void scanC_kernel(const unsigned int* __restrict__ local,
                             const unsigned int* __restrict__ blkSum, int N, int nb,
                             unsigned int* __restrict__ off, unsigned int* __restrict__ cur) {
    int i = blockIdx.x * blockDim.x + threadIdx.x;
    if (i < N) {
        unsigned int v = local[i] + blkSum[i / SCAN_TILE];
        off[i] = v;
        cur[i] = v;
    } else if (i == N) {
        off[N] = blkSum[nb];
    }
}

// bucket edges by target; pack (src bit-cast, weight) into float2
__global__ void scatter_kernel(const int* __restrict__ row, const int* __restrict__ col,
                               int E, unsigned int* __restrict__ cur,
                               const float* __restrict__ dinv, float2* __restrict__ ew) {
    int e = blockIdx.x * blockDim.x + threadIdx.x;
    if (e >= E) return;
    int r = row[e];
    int c = col[e];
    unsigned int p = atomicAdd(&cur[c], 1u);
    float2 v;
    v.x = __int_as_float(r);
    v.y = dinv[r] * dinv[c];
    ew[p] = v;
}

// ---------------- W -> bf16 hi/lo fragments (runs once, tiny) ----------------
// Fragment order for mfma_f32_16x16x32_bf16 B-operand:
//   frag index (n, kc, lane): element W[16n + (lane&15)][kc*32 + (lane>>4)*8 + j]
__global__ __launch_bounds__(256) void wprep_kernel(const float* __restrict__ W,
                                                    short8v* __restrict__ Whi,
                                                    short8v* __restrict__ Wlo) {
    int t = blockIdx.x * 256 + threadIdx.x;  // 0..1023
    int n = t >> 9;
    int kc = (t >> 6) & 7;
    int l = t & 63;
    int ch = 16 * n + (l & 15);
    int k0 = kc * 32 + (l >> 4) * 8;
    const float* wp = W + ch * IN_DIM + k0;
    short8v hi, lo;
#pragma unroll
    for (int j = 0; j < 8; ++j) {
        float f = wp[j];
        unsigned u = __float_as_uint(f);
        hi[j] = (short)(u >> 16);                       // truncated bf16 hi
        float fh = __uint_as_float(u & 0xffff0000u);
        float r = f - fh;                               // exact residual
        unsigned v = __float_as_uint(r);
        lo[j] = (short)((v + 0x7fffu + ((v >> 16) & 1u)) >> 16);  // rne bf16
    }
    Whi[t] = hi;
    Wlo[t] = lo;
}

// ---------------- h = x @ W^T + b  (MFMA, bf16 hi/lo = ~f32 precision) -------
// wave = 64 rows (4 M-tiles of 16); block = 4 waves = 256 rows.
// A frag: lane l holds x[16m + (l&15)][kc*32 + (l>>4)*8 + j], j=0..7
// C/D: col = l&15 (channel within 16), row = (l>>4)*4 + reg   [m89-verified]

__device__ __forceinline__ void cvt_hilo(float4 a, float4 c, short8v& hi, short8v& lo) {
    float f[8] = {a.x, a.y, a.z, a.w, c.x, c.y, c.z, c.w};
#pragma unroll
    for (int j = 0; j < 8; ++j) {
        unsigned u = __float_as_uint(f[j]);
        hi[j] = (short)(u >> 16);
        float fh = __uint_as_float(u & 0xffff0000u);
        float r = f[j] - fh;
        unsigned v = __float_as_uint(r);
        lo[j] = (short)((v + 0x7fffu + ((v >> 16) & 1u)) >> 16);
    }
}

__global__ __launch_bounds__(256) void gemm_kernel(const float* __restrict__ x,
                                                   const short8v* __restrict__ Whi,
                                                   const short8v* __restrict__ Wlo,
                                                   const float* __restrict__ b, int N,
                                                   float* __restrict__ h) {
    int wid = threadIdx.x >> 6;
    int l = threadIdx.x & 63;
    int lr = l & 15;       // row-in-tile / channel-in-tile
    int lk = l >> 4;       // k-group 0..3
    int r0 = blockIdx.x * 256 + wid * 64;

    int arow[4];
#pragma unroll
    for (int m = 0; m < 4; ++m) {
        int r = r0 + 16 * m + lr;
        arow[m] = (r < N) ? r : (N - 1);  // clamp (stores are guarded)
    }

    float4v acc[4][2];
#pragma unroll
    for (int m = 0; m < 4; ++m)
#pragma unroll
        for (int n = 0; n < 2; ++n) acc[m][n] = (float4v)(0.0f);

#pragma unroll
    for (int kc = 0; kc < 8; ++kc) {
        short8v bh0 = Whi[(0 * 8 + kc) * 64 + l];
        short8v bh1 = Whi[(1 * 8 + kc) * 64 + l];
        short8v bl0 = Wlo[(0 * 8 + kc) * 64 + l];
        short8v bl1 = Wlo[(1 * 8 + kc) * 64 + l];
#pragma unroll
        for (int m = 0; m < 4; ++m) {
            const float* xp = x + (size_t)arow[m] * IN_DIM + kc * 32 + lk * 8;
            float4 xa = *(const float4*)xp;
            float4 xc = *(const float4*)(xp + 4);
            short8v ah, al;
            cvt_hilo(xa, xc, ah, al);
            acc[m][0] = __builtin_amdgcn_mfma_f32_16x16x32_bf16(ah, bh0, acc[m][0], 0, 0, 0);
            acc[m][1] = __builtin_amdgcn_mfma_f32_16x16x32_bf16(ah, bh1, acc[m][1], 0, 0, 0);
            acc[m][0] = __builtin_amdgcn_mfma_f32_16x16x32_bf16(al, bh0, acc[m][0], 0, 0, 0);
            acc[m][1] = __builtin_amdgcn_mfma_f32_16x16x32_bf16(al, bh1, acc[m][1], 0, 0, 0);
            acc[m][0] = __builtin_amdgcn_mfma_f32_16x16x32_bf16(ah, bl0, acc[m][0], 0, 0, 0);
            acc[m][1] = __builtin_amdgcn_mfma_f32_16x16x32_bf16(ah, bl1, acc[m][1], 0, 0, 0);
        }
    }

    float bb[2];
    bb[0] = b[lr];
    bb[1] = b[16 + lr];
#pragma unroll
    for (int m = 0; m < 4; ++m) {
#pragma unroll
        for (int n = 0; n < 2; ++n) {
            int ch = 16 * n + lr;
#pragma unroll
            for (int reg = 0; reg < 4; ++reg) {
                int row = r0 + 16 * m + 4 * lk + reg;
                if (row < N) h[(size_t)row * OUT_DIM + ch] = acc[m][n][reg] + bb[n];
            }
        }
    }
}

// ---------------- one APPNP propagation step ----------------
// 32 lanes per node (ch = lane&31); 16 gathers in flight; bf16 z intermediates

template <bool IN_BF, bool OUT_BF>
__global__ __launch_bounds__(256) void spmv_kernel(
    const float2* __restrict__ ew, const unsigned int* __restrict__ off,
    const float* __restrict__ dinv, const void* __restrict__ zin_v,
    const float* __restrict__ h, const float* __restrict__ prelu_a, int N,
    void* __restrict__ zout_v) {
    const float* zf = (const float*)zin_v;
    const ushort* zb = (const ushort*)zin_v;
    int tid = threadIdx.x;
    int ch = tid & 31;
    int node = blockIdx.x * 8 + (tid >> 5);
    if (node >= N) return;
    unsigned nidx = (unsigned)node * OUT_DIM + ch;
    unsigned e = off[node];
    unsigned end = off[node + 1];
    float di = dinv[node];
    float self;
    if (IN_BF) {
        unsigned u = (unsigned)zb[nidx] << 16;
        self = __uint_as_float(u);
    } else {
        self = zf[nidx];
    }
    float hterm = 0.2f * h[nidx];
    float acc0 = di * di * self;  // self loop
    float acc1 = 0.f, acc2 = 0.f, acc3 = 0.f;

    auto gz = [&](float sbits) -> float {
        unsigned i = (unsigned)__float_as_int(sbits) * OUT_DIM + ch;
        if (IN_BF) {
            unsigned u = (unsigned)zb[i] << 16;
            return __uint_as_float(u);
        }
        return zf[i];
    };

    // 16-deep pipelined main loop
    while (e + 16 <= end) {
        float2 p[16];
#pragma unroll
        for (int j = 0; j < 16; ++j) p[j] = ew[e + j];
        float zv[16];
#pragma unroll
        for (int j = 0; j < 16; ++j) zv[j] = gz(p[j].x);
#pragma unroll
        for (int j = 0; j < 16; ++j) {
            float t = p[j].y * zv[j];
            if ((j & 3) == 0) acc0 += t;
            else if ((j & 3) == 1) acc1 += t;
            else if ((j & 3) == 2) acc2 += t;
            else acc3 += t;
        }
        e += 16;
    }
    while (e + 4 <= end) {
        float2 p0 = ew[e], p1 = ew[e + 1], p2 = ew[e + 2], p3 = ew[e + 3];
        acc0 += p0.y * gz(p0.x);
        acc1 += p1.y * gz(p1.x);
        acc2 += p2.y * gz(p2.x);
        acc3 += p3.y * gz(p3.x);
        e += 4;
    }
    for (; e < end; ++e) {
        float2 p = ew[e];
        acc0 += p.y * gz(p.x);
    }

    float out = 0.8f * ((acc0 + acc1) + (acc2 + acc3)) + hterm;
    if (OUT_BF) {
        unsigned u = __float_as_uint(out);
        ushort r = (ushort)((u + 0x7fffu + ((u >> 16) & 1u)) >> 16);  // rne bf16
        ((ushort*)zout_v)[nidx] = r;
    } else {
        float a = prelu_a[ch];
        out = (out >= 0.f) ? out : a * out;
        ((float*)zout_v)[nidx] = out;
    }
}

// ---------------- launcher ----------------

extern "C" void kernel_launch(void* const* d_in, const int* in_sizes, int n_in,
                              void* d_out, int out_size, void* d_ws, size_t ws_size,
                              hipStream_t stream) {
    const float* x = (const float*)d_in[0];
    const int* ei = (const int*)d_in[1];
    const float* W = (const float*)d_in[2];
    const float* b = (const float*)d_in[3];
    const float* pa = (const float*)d_in[4];

    int N = in_sizes[0] / IN_DIM;
    int E = in_sizes[1] / 2;
    const int* row = ei;      // edge_index[0] = source
    const int* col = ei + E;  // edge_index[1] = target
    int nb = (N + SCAN_TILE - 1) / SCAN_TILE;

    char* ws = (char*)d_ws;
    size_t o = 0;
    auto alloc = [&](size_t bytes) -> void* {
        void* p = ws + o;
        o += (bytes + 255) & ~(size_t)255;
        return p;
    };
    unsigned int* d_cnt = (unsigned int*)alloc((size_t)N * 4);
    unsigned int* d_local = (unsigned int*)alloc((size_t)N * 4);
    unsigned int* d_blkSum = (unsigned int*)alloc(4096);
    unsigned int* d_off = (unsigned int*)alloc((size_t)(N + 1) * 4);
    unsigned int* d_cur = (unsigned int*)alloc((size_t)N * 4);
    float* d_dinv = (float*)alloc((size_t)N * 4);
    float2* d_ew = (float2*)alloc((size_t)E * 8);
    float* d_h = (float*)alloc((size_t)N * OUT_DIM * 4);
    ushort* d_zA = (ushort*)alloc((size_t)N * OUT_DIM * 2);
    ushort* d_zB = (ushort*)alloc((size_t)N * OUT_DIM * 2);
    short8v* d_Whi = (short8v*)alloc(16384);
    short8v* d_Wlo = (short8v*)alloc(16384);
    (void)ws_size;

    hipMemsetAsync(d_cnt, 0, (size_t)N * 4, stream);

    hist_kernel<<<(E + 255) / 256, 256, 0, stream>>>(col, E, d_cnt);
    scanA_kernel<<<nb, 256, 0, stream>>>(d_cnt, N, d_local, d_blkSum, d_dinv);
    scanB_kernel<<<1, 256, 0, stream>>>(d_blkSum, nb);
    scanC_kernel<<<(N + 256) / 256, 256, 0, stream>>>(d_local, d_blkSum, N, nb, d_off, d_cur);
    scatter_kernel<<<(E + 255) / 256, 256, 0, stream>>>(row, col, E, d_cur, d_dinv, d_ew);
    wprep_kernel<<<4, 256, 0, stream>>>(W, d_Whi, d_Wlo);
    gemm_kernel<<<(N + 255) / 256, 256, 0, stream>>>(x, d_Whi, d_Wlo, b, N, d_h);

    int grid = (N + 7) / 8;
    // iter 0: f32 h -> bf16 zA
    spmv_kernel<false, true><<<grid, 256, 0, stream>>>(d_ew, d_off, d_dinv, d_h, d_h, pa, N,
                                                       d_zA);
    // iters 1..8: bf16 -> bf16 (ping-pong)
    ushort* bufs[2] = {d_zA, d_zB};
    for (int it = 1; it < KITER - 1; ++it) {
        spmv_kernel<true, true><<<grid, 256, 0, stream>>>(
            d_ew, d_off, d_dinv, bufs[(it + 1) & 1], d_h, pa, N, bufs[it & 1]);
    }
    // iter 9: bf16 -> f32 out + PReLU
    spmv_kernel<true, false><<<grid, 256, 0, stream>>>(d_ew, d_off, d_dinv, bufs[1], d_h, pa,
                                                       N, d_out);
}